// Round 3
// baseline (271.130 us; speedup 1.0000x reference)
//
#include <hip/hip_runtime.h>
#include <hip/hip_bf16.h>

#define NH 4
#define HD 64
#define HID 256
#define SS 4096
#define KP 96   // augmented Q/K pitch (64 head dims + 32 group-onehot dims)

typedef float f4 __attribute__((ext_vector_type(4)));
typedef float f16v __attribute__((ext_vector_type(16)));
typedef short bf8 __attribute__((ext_vector_type(8)));   // 8 bf16 (4 VGPRs)

static __device__ __forceinline__ float fast_exp2(float x) {
#if __has_builtin(__builtin_amdgcn_exp2f)
    return __builtin_amdgcn_exp2f(x);
#else
    float r; asm("v_exp_f32 %0, %1" : "=v"(r) : "v"(x)); return r;
#endif
}

static __device__ __forceinline__ unsigned pack2(float a, float b) {
    unsigned ua = (unsigned)__bfloat16_as_ushort(__float2bfloat16(a));
    unsigned ub = (unsigned)__bfloat16_as_ushort(__float2bfloat16(b));
    return ua | (ub << 16);
}

// ---------------------------------------------------------------------------
// Setup: derive codon->group-id map (rank of group representative) and
// beta*log2e from the synonymy matrix. 1 block, 64 threads (one wave).
// ---------------------------------------------------------------------------
__global__ void setup_kernel(const float* __restrict__ syn,
                             int* __restrict__ gid, float* __restrict__ betaP)
{
    const int lane = threadIdx.x;          // 0..63
    int rep = 64;
    for (int j = 63; j >= 0; --j)
        if (syn[lane * 64 + j] != 0.0f) rep = j;   // first nonzero = group min
    if (rep == 64) rep = lane;
    unsigned long long m = __ballot(rep == lane);  // group representatives
    int id = (int)__popcll(m & ((2ull << rep) - 1ull)) - 1;
    if (id < 0) id = 0;
    gid[lane] = id;                                 // 0..20 (<=31)
    if (lane == 0) *betaP = syn[0] * 1.44269504088896f;  // diag = beta
}

// ---------------------------------------------------------------------------
// QKV projection: X(8192x256) @ W^T + b.
// q scaled by 0.125*log2e (folds softmax scale + exp2 base change).
// q,k bf16 [b][h][s][96] (dims 64..95 = group onehot); v bf16 [b][h][d][s].
// ---------------------------------------------------------------------------
__global__ __launch_bounds__(256)
void qkv_proj_kernel(const float* __restrict__ x,
                     const float* __restrict__ wq, const float* __restrict__ bq,
                     const float* __restrict__ wk, const float* __restrict__ bk,
                     const float* __restrict__ wv, const float* __restrict__ bv,
                     const int* __restrict__ codons,
                     const int* __restrict__ gid, const float* __restrict__ betaP,
                     __hip_bfloat16* __restrict__ qb,
                     __hip_bfloat16* __restrict__ kb,
                     __hip_bfloat16* __restrict__ vtb)
{
    const int nt = blockIdx.x;            // 0..11
    const int m0 = blockIdx.y * 64;       // row tile
    const int proj = nt >> 2;             // 0=q 1=k 2=v
    const int n0 = (nt & 3) * 64;         // col within projection
    const float* __restrict__ w  = (proj == 0) ? wq : (proj == 1) ? wk : wv;
    const float* __restrict__ bs = (proj == 0) ? bq : (proj == 1) ? bk : bv;

    __shared__ __align__(16) float xs[64][68];
    __shared__ __align__(16) float wt[64][64];

    const int tid = threadIdx.x;
    const int tx = tid & 15, ty = tid >> 4;

    float acc[4][4] = {};

    for (int k0 = 0; k0 < 256; k0 += 64) {
        {
            const int c4 = (tid & 15) * 4;
            const int r0 = tid >> 4;
            #pragma unroll
            for (int p = 0; p < 4; ++p) {
                const int r = r0 + p * 16;
                *(f4*)&xs[r][c4] = *(const f4*)&x[(size_t)(m0 + r) * HID + k0 + c4];
            }
        }
        {
            const int col = tid & 63;
            const int kb4 = (tid >> 6) * 16;
            #pragma unroll
            for (int kk = 0; kk < 16; kk += 4) {
                f4 v = *(const f4*)&w[(size_t)(n0 + col) * HID + k0 + kb4 + kk];
                wt[kb4 + kk + 0][col] = v[0];
                wt[kb4 + kk + 1][col] = v[1];
                wt[kb4 + kk + 2][col] = v[2];
                wt[kb4 + kk + 3][col] = v[3];
            }
        }
        __syncthreads();

        for (int kk = 0; kk < 64; kk += 4) {
            f4 xv[4], wr[4];
            #pragma unroll
            for (int i = 0; i < 4; ++i) xv[i] = *(const f4*)&xs[ty * 4 + i][kk];
            #pragma unroll
            for (int t = 0; t < 4; ++t) wr[t] = *(const f4*)&wt[kk + t][tx * 4];
            #pragma unroll
            for (int i = 0; i < 4; ++i)
                #pragma unroll
                for (int j = 0; j < 4; ++j)
                    acc[i][j] += xv[i][0] * wr[0][j] + xv[i][1] * wr[1][j]
                               + xv[i][2] * wr[2][j] + xv[i][3] * wr[3][j];
        }
        __syncthreads();
    }

    const float QSCALE = 0.18033688011112042f;   // 0.125 * log2(e)
    const f4 bias4 = *(const f4*)&bs[n0 + tx * 4];
    #pragma unroll
    for (int i = 0; i < 4; ++i) {
        const int m = m0 + ty * 4 + i;
        const int bidx = m >> 12;
        const int s = m & 4095;
        #pragma unroll
        for (int j = 0; j < 4; ++j) {
            const int n = n0 + tx * 4 + j;
            const int hh = n >> 6;
            const int dd = n & 63;
            float v = acc[i][j] + bias4[j];
            if (proj == 0) {
                v *= QSCALE;
                qb[(((size_t)bidx * NH + hh) * SS + s) * KP + dd] = __float2bfloat16(v);
            } else if (proj == 1) {
                kb[(((size_t)bidx * NH + hh) * SS + s) * KP + dd] = __float2bfloat16(v);
            } else {
                vtb[(((size_t)bidx * NH + hh) * HD + dd) * SS + s] = __float2bfloat16(v);
            }
        }
    }

    // ---- augmentation dims 64..95: group onehot (q: beta*log2e, k: 1.0)
    if ((nt & 3) == 0 && proj < 2) {
        const float bl2e = *betaP;
        const int r = tid >> 2, hh = tid & 3;   // 64 rows x 4 heads
        const int m = m0 + r;
        const int bidx = m >> 12;
        const int s = m & 4095;
        const int cg = gid[codons[bidx * SS + s] & 63];
        __hip_bfloat16* dst = (proj == 0 ? qb : kb)
                              + (((size_t)(bidx * NH + hh) * SS + s) * KP + 64);
        const bf8 z = {0, 0, 0, 0, 0, 0, 0, 0};
        #pragma unroll
        for (int j = 0; j < 4; ++j) *(bf8*)&dst[j * 8] = z;
        dst[cg] = __float2bfloat16(proj == 0 ? bl2e : 1.0f);
    }
}

// ---------------------------------------------------------------------------
// Flash attention, swapped-operand 32x32x16 MFMA, bias fused into MFMA via
// group-onehot dims, no-max exp2 softmax (statistically safe score range).
// Block = 256 thr = 4 warps = 2 q-tiles (32 rows) x 2 KV halves.
// ---------------------------------------------------------------------------
__global__ __launch_bounds__(256)
void attn_kernel(const __hip_bfloat16* __restrict__ qg,
                 const __hip_bfloat16* __restrict__ kg,
                 const __hip_bfloat16* __restrict__ vtg,
                 float* __restrict__ aout)
{
    const int bid = blockIdx.x;
    const int bh = bid & 7;
    const int b = bh >> 2, h = bh & 3;
    const int qg64 = bid >> 3;            // 0..63
    const int tid = threadIdx.x;
    const int w = tid >> 6;
    const int lane = tid & 63;
    const int q5 = lane & 31;
    const int hi = lane >> 5;
    const int qt = w & 1;
    const int half = w >> 1;
    const int wl = w & 1;

    __shared__ __align__(16) __hip_bfloat16 k_sh[2][2][64][KP];   // 48 KB
    __shared__ __align__(16) __hip_bfloat16 vt_sh[2][2][64][64];  // 32 KB

    const size_t kvbase = (size_t)(b * NH + h) * SS * KP;
    const size_t vtbase = (size_t)(b * NH + h) * HD * SS;
    const int qrow = qg64 * 64 + qt * 32 + q5;

    // ---- Q fragments (B operand), 96 dims
    const size_t qoff = ((size_t)(b * NH + h) * SS + qrow) * KP;
    bf8 qf[6];
    #pragma unroll
    for (int ks = 0; ks < 6; ++ks)
        qf[ks] = *(const bf8*)&qg[qoff + ks * 16 + hi * 8];

    // ---- staging: 128 lanes per kv-stream; row = il>>1, side = il&1
    const int il = wl * 64 + lane;
    const int srow = il >> 1;
    const int side = il & 1;
    // chunk assignment pairs disjoint bank-group sets per store instruction
    const int CK0[6] = {0, 1, 2, 3, 8, 9};
    const int CK1[6] = {4, 5, 6, 7, 11, 10};

    bf8 gk[6], gv[4];

    auto swz = [](int c, int r) {
        return (c < 8) ? (c ^ (r & 7)) : (8 + ((c & 3) ^ (r & 3)));
    };
    auto load_tile = [&](int t) {
        const int kv0 = half * 2048 + t * 64;
        #pragma unroll
        for (int p = 0; p < 6; ++p) {
            const int c = side ? CK1[p] : CK0[p];
            gk[p] = *(const bf8*)&kg[kvbase + (size_t)(kv0 + srow) * KP + c * 8];
        }
        #pragma unroll
        for (int p = 0; p < 4; ++p)
            gv[p] = *(const bf8*)&vtg[vtbase + (size_t)srow * SS + kv0 + (side * 4 + p) * 8];
    };
    auto write_tile = [&](int buf) {
        #pragma unroll
        for (int p = 0; p < 6; ++p) {
            const int c = side ? CK1[p] : CK0[p];
            *(bf8*)&k_sh[half][buf][srow][swz(c, srow) * 8] = gk[p];
        }
        #pragma unroll
        for (int p = 0; p < 4; ++p) {
            const int c = side * 4 + p;
            *(bf8*)&vt_sh[half][buf][srow][(c ^ (srow & 7)) * 8] = gv[p];
        }
    };

    f16v oacc0, oacc1;
    #pragma unroll
    for (int r = 0; r < 16; ++r) { oacc0[r] = 0.0f; oacc1[r] = 0.0f; }
    float lrun = 0.0f;

    load_tile(0);
    write_tile(0);
    __syncthreads();

    for (int t = 0; t < 32; ++t) {
        const int buf = t & 1;
        if (t + 1 < 32) load_tile(t + 1);

        // ---- QK^T (swapped): D[key][q], 96-dim dot (64 qk + 32 bias onehot)
        bf8 kf0[6], kf1[6];
        #pragma unroll
        for (int ks = 0; ks < 6; ++ks) {
            const int slot = swz(ks * 2 + hi, q5) * 8;
            kf0[ks] = *(const bf8*)&k_sh[half][buf][q5][slot];
            kf1[ks] = *(const bf8*)&k_sh[half][buf][32 + q5][slot];
        }
        f16v sA, sB;
        #pragma unroll
        for (int r = 0; r < 16; ++r) { sA[r] = 0.0f; sB[r] = 0.0f; }
        __builtin_amdgcn_s_setprio(1);
        #pragma unroll
        for (int ks = 0; ks < 6; ++ks) {
            sA = __builtin_amdgcn_mfma_f32_32x32x16_bf16(kf0[ks], qf[ks], sA, 0, 0, 0);
            sB = __builtin_amdgcn_mfma_f32_32x32x16_bf16(kf1[ks], qf[ks], sB, 0, 0, 0);
        }
        __builtin_amdgcn_s_setprio(0);

        // ---- p = 2^s (no max subtraction; fp32 range is ample)
        float ls = 0.0f;
        #pragma unroll
        for (int r = 0; r < 16; ++r) { sA[r] = fast_exp2(sA[r]); ls += sA[r]; }
        #pragma unroll
        for (int r = 0; r < 16; ++r) { sB[r] = fast_exp2(sB[r]); ls += sB[r]; }
        lrun += ls;

        // ---- P -> bf16 dwords; exchange halves to build PV B-fragments
        unsigned dwv[2][4][2];
        #pragma unroll
        for (int j = 0; j < 4; ++j)
            #pragma unroll
            for (int c = 0; c < 2; ++c) {
                dwv[0][j][c] = pack2(sA[j * 4 + 2 * c], sA[j * 4 + 2 * c + 1]);
                dwv[1][j][c] = pack2(sB[j * 4 + 2 * c], sB[j * 4 + 2 * c + 1]);
            }
        unsigned rc[2][2][2];
        #pragma unroll
        for (int t2 = 0; t2 < 2; ++t2)
            #pragma unroll
            for (int k1 = 0; k1 < 2; ++k1)
                #pragma unroll
                for (int c = 0; c < 2; ++c) {
                    const unsigned snd = hi ? dwv[t2][2 * k1][c] : dwv[t2][2 * k1 + 1][c];
                    rc[t2][k1][c] = (unsigned)__shfl_xor((int)snd, 32, 64);
                }

        // ---- PV: D[d][q], A = V^T frag, B = P frag
        __builtin_amdgcn_s_setprio(1);
        #pragma unroll
        for (int ks = 0; ks < 4; ++ks) {
            const int t2 = ks >> 1, k1 = ks & 1;
            union { unsigned u[4]; bf8 v; } pf;
            pf.u[0] = hi ? rc[t2][k1][0] : dwv[t2][2 * k1][0];
            pf.u[1] = hi ? rc[t2][k1][1] : dwv[t2][2 * k1][1];
            pf.u[2] = hi ? dwv[t2][2 * k1 + 1][0] : rc[t2][k1][0];
            pf.u[3] = hi ? dwv[t2][2 * k1 + 1][1] : rc[t2][k1][1];
            const int slot = ((ks * 2 + hi) ^ (q5 & 7)) * 8;
            const bf8 vf0 = *(const bf8*)&vt_sh[half][buf][q5][slot];
            const bf8 vf1 = *(const bf8*)&vt_sh[half][buf][32 + q5][slot];
            oacc0 = __builtin_amdgcn_mfma_f32_32x32x16_bf16(vf0, pf.v, oacc0, 0, 0, 0);
            oacc1 = __builtin_amdgcn_mfma_f32_32x32x16_bf16(vf1, pf.v, oacc1, 0, 0, 0);
        }
        __builtin_amdgcn_s_setprio(0);

        __syncthreads();
        if (t + 1 < 32) write_tile((t + 1) & 1);
        __syncthreads();
    }

    // ---- merge halves: plain sums (no exp factors needed)
    const float ltot = lrun + __shfl_xor(lrun, 32, 64);
    float* o_sh = (float*)&k_sh[0][0][0][0];      // 2*32 rows x 68 pitch
    float* l_sh = o_sh + 2 * 32 * 68;
    if (half == 1) {
        #pragma unroll
        for (int dt = 0; dt < 2; ++dt)
            #pragma unroll
            for (int j = 0; j < 4; ++j) {
                f4 tv;
                #pragma unroll
                for (int i = 0; i < 4; ++i)
                    tv[i] = dt ? oacc1[j * 4 + i] : oacc0[j * 4 + i];
                *(f4*)&o_sh[(qt * 32 + q5) * 68 + dt * 32 + 8 * j + 4 * hi] = tv;
            }
        if (hi == 0) l_sh[qt * 32 + q5] = ltot;
    }
    __syncthreads();
    if (half == 0) {
        const float inv = 1.0f / (ltot + l_sh[qt * 32 + q5]);
        #pragma unroll
        for (int dt = 0; dt < 2; ++dt)
            #pragma unroll
            for (int j = 0; j < 4; ++j) {
                const int d = dt * 32 + 8 * j + 4 * hi;
                const f4 o1 = *(const f4*)&o_sh[(qt * 32 + q5) * 68 + d];
                f4 tv;
                #pragma unroll
                for (int i = 0; i < 4; ++i)
                    tv[i] = ((dt ? oacc1[j * 4 + i] : oacc0[j * 4 + i]) + o1[i]) * inv;
                *(f4*)&aout[((size_t)b * SS + qrow) * HID + h * HD + d] = tv;
            }
    }
}

// ---------------------------------------------------------------------------
// Output projection: A(8192x256) @ Wo^T + bo -> out fp32. grid (4, 128).
// ---------------------------------------------------------------------------
__global__ __launch_bounds__(256)
void out_proj_kernel(const float* __restrict__ a, const float* __restrict__ wo,
                     const float* __restrict__ bo, float* __restrict__ out)
{
    const int n0 = blockIdx.x * 64;
    const int m0 = blockIdx.y * 64;

    __shared__ __align__(16) float xs[64][68];
    __shared__ __align__(16) float wt[64][64];

    const int tid = threadIdx.x;
    const int tx = tid & 15, ty = tid >> 4;

    float acc[4][4] = {};

    for (int k0 = 0; k0 < 256; k0 += 64) {
        {
            const int c4 = (tid & 15) * 4;
            const int r0 = tid >> 4;
            #pragma unroll
            for (int p = 0; p < 4; ++p) {
                const int r = r0 + p * 16;
                *(f4*)&xs[r][c4] = *(const f4*)&a[(size_t)(m0 + r) * HID + k0 + c4];
            }
        }
        {
            const int col = tid & 63;
            const int kb4 = (tid >> 6) * 16;
            #pragma unroll
            for (int kk = 0; kk < 16; kk += 4) {
                f4 v = *(const f4*)&wo[(size_t)(n0 + col) * HID + k0 + kb4 + kk];
                wt[kb4 + kk + 0][col] = v[0];
                wt[kb4 + kk + 1][col] = v[1];
                wt[kb4 + kk + 2][col] = v[2];
                wt[kb4 + kk + 3][col] = v[3];
            }
        }
        __syncthreads();

        for (int kk = 0; kk < 64; kk += 4) {
            f4 xv[4], wr[4];
            #pragma unroll
            for (int i = 0; i < 4; ++i) xv[i] = *(const f4*)&xs[ty * 4 + i][kk];
            #pragma unroll
            for (int t = 0; t < 4; ++t) wr[t] = *(const f4*)&wt[kk + t][tx * 4];
            #pragma unroll
            for (int i = 0; i < 4; ++i)
                #pragma unroll
                for (int j = 0; j < 4; ++j)
                    acc[i][j] += xv[i][0] * wr[0][j] + xv[i][1] * wr[1][j]
                               + xv[i][2] * wr[2][j] + xv[i][3] * wr[3][j];
        }
        __syncthreads();
    }

    const f4 bias4 = *(const f4*)&bo[n0 + tx * 4];
    #pragma unroll
    for (int i = 0; i < 4; ++i) {
        const int m = m0 + ty * 4 + i;
        f4 v;
        #pragma unroll
        for (int j = 0; j < 4; ++j) v[j] = acc[i][j] + bias4[j];
        *(f4*)&out[(size_t)m * HID + n0 + tx * 4] = v;
    }
}

extern "C" void kernel_launch(void* const* d_in, const int* in_sizes, int n_in,
                              void* d_out, int out_size, void* d_ws, size_t ws_size,
                              hipStream_t stream)
{
    (void)in_sizes; (void)n_in; (void)out_size; (void)ws_size;
    const float* x        = (const float*)d_in[0];
    const int*   codons   = (const int*)d_in[1];
    const float* syn_bias = (const float*)d_in[2];
    const float* wq = (const float*)d_in[3];
    const float* bq = (const float*)d_in[4];
    const float* wk = (const float*)d_in[5];
    const float* bk = (const float*)d_in[6];
    const float* wv = (const float*)d_in[7];
    const float* bv = (const float*)d_in[8];
    const float* wo = (const float*)d_in[9];
    const float* bo = (const float*)d_in[10];
    float* out = (float*)d_out;

    char* ws = (char*)d_ws;
    int*   gid   = (int*)(ws);                       // 256 B
    float* betaP = (float*)(ws + 256);               // 4 B
    __hip_bfloat16* qb  = (__hip_bfloat16*)(ws + (size_t)(1u << 20));       // 6.29 MB
    __hip_bfloat16* kb  = (__hip_bfloat16*)(ws + (size_t)7340032u);         // 6.29 MB
    __hip_bfloat16* vtb = (__hip_bfloat16*)(ws + (size_t)13631488u);        // 4 MB
    float* aout         = (float*)(ws + (size_t)17825792u);                 // 8 MB

    setup_kernel<<<1, 64, 0, stream>>>(syn_bias, gid, betaP);
    qkv_proj_kernel<<<dim3(12, 128), 256, 0, stream>>>(x, wq, bq, wk, bk, wv, bv,
                                                       codons, gid, betaP, qb, kb, vtb);
    attn_kernel<<<512, 256, 0, stream>>>(qb, kb, vtb, aout);
    out_proj_kernel<<<dim3(4, 128), 256, 0, stream>>>(aout, wo, bo, out);
}

// Round 4
// 244.708 us; speedup vs baseline: 1.1080x; 1.1080x over previous
//
#include <hip/hip_runtime.h>
#include <hip/hip_bf16.h>

#define NH 4
#define HD 64
#define HID 256
#define SS 4096
#define KP 96   // augmented Q/K pitch (64 head dims + 32 group-onehot dims)

typedef float f4 __attribute__((ext_vector_type(4)));
typedef float f16v __attribute__((ext_vector_type(16)));
typedef short bf8 __attribute__((ext_vector_type(8)));   // 8 bf16 (4 VGPRs)

static __device__ __forceinline__ float fast_exp2(float x) {
#if __has_builtin(__builtin_amdgcn_exp2f)
    return __builtin_amdgcn_exp2f(x);
#else
    float r; asm("v_exp_f32 %0, %1" : "=v"(r) : "v"(x)); return r;
#endif
}

static __device__ __forceinline__ unsigned pack2(float a, float b) {
    unsigned ua = (unsigned)__bfloat16_as_ushort(__float2bfloat16(a));
    unsigned ub = (unsigned)__bfloat16_as_ushort(__float2bfloat16(b));
    return ua | (ub << 16);
}

// ---------------------------------------------------------------------------
// Setup: codon->group-id map + beta*log2e, from the synonymy matrix.
// ---------------------------------------------------------------------------
__global__ void setup_kernel(const float* __restrict__ syn,
                             int* __restrict__ gid, float* __restrict__ betaP)
{
    const int lane = threadIdx.x;          // 0..63
    int rep = 64;
    for (int j = 63; j >= 0; --j)
        if (syn[lane * 64 + j] != 0.0f) rep = j;   // first nonzero = group min
    if (rep == 64) rep = lane;
    unsigned long long m = __ballot(rep == lane);  // group representatives
    int id = (int)__popcll(m & ((2ull << rep) - 1ull)) - 1;
    if (id < 0) id = 0;
    gid[lane] = id;                                 // 0..20 (<=31)
    if (lane == 0) *betaP = syn[0] * 1.44269504088896f;  // diag = beta
}

// ---------------------------------------------------------------------------
// QKV projection: X(8192x256) @ W^T + b.
// q scaled by 0.125*log2e. q,k bf16 [b][h][s][96] (dims 64..95 = group
// onehot; q side scaled by beta*log2e, k side 1.0); v bf16 [b][h][d][s].
// ---------------------------------------------------------------------------
__global__ __launch_bounds__(256)
void qkv_proj_kernel(const float* __restrict__ x,
                     const float* __restrict__ wq, const float* __restrict__ bq,
                     const float* __restrict__ wk, const float* __restrict__ bk,
                     const float* __restrict__ wv, const float* __restrict__ bv,
                     const int* __restrict__ codons,
                     const int* __restrict__ gid, const float* __restrict__ betaP,
                     __hip_bfloat16* __restrict__ qb,
                     __hip_bfloat16* __restrict__ kb,
                     __hip_bfloat16* __restrict__ vtb)
{
    const int nt = blockIdx.x;            // 0..11
    const int m0 = blockIdx.y * 64;       // row tile
    const int proj = nt >> 2;             // 0=q 1=k 2=v
    const int n0 = (nt & 3) * 64;         // col within projection
    const float* __restrict__ w  = (proj == 0) ? wq : (proj == 1) ? wk : wv;
    const float* __restrict__ bs = (proj == 0) ? bq : (proj == 1) ? bk : bv;

    __shared__ __align__(16) float xs[64][68];
    __shared__ __align__(16) float wt[64][64];

    const int tid = threadIdx.x;
    const int tx = tid & 15, ty = tid >> 4;

    float acc[4][4] = {};

    for (int k0 = 0; k0 < 256; k0 += 64) {
        {
            const int c4 = (tid & 15) * 4;
            const int r0 = tid >> 4;
            #pragma unroll
            for (int p = 0; p < 4; ++p) {
                const int r = r0 + p * 16;
                *(f4*)&xs[r][c4] = *(const f4*)&x[(size_t)(m0 + r) * HID + k0 + c4];
            }
        }
        {
            const int col = tid & 63;
            const int kb4 = (tid >> 6) * 16;
            #pragma unroll
            for (int kk = 0; kk < 16; kk += 4) {
                f4 v = *(const f4*)&w[(size_t)(n0 + col) * HID + k0 + kb4 + kk];
                wt[kb4 + kk + 0][col] = v[0];
                wt[kb4 + kk + 1][col] = v[1];
                wt[kb4 + kk + 2][col] = v[2];
                wt[kb4 + kk + 3][col] = v[3];
            }
        }
        __syncthreads();

        for (int kk = 0; kk < 64; kk += 4) {
            f4 xv[4], wr[4];
            #pragma unroll
            for (int i = 0; i < 4; ++i) xv[i] = *(const f4*)&xs[ty * 4 + i][kk];
            #pragma unroll
            for (int t = 0; t < 4; ++t) wr[t] = *(const f4*)&wt[kk + t][tx * 4];
            #pragma unroll
            for (int i = 0; i < 4; ++i)
                #pragma unroll
                for (int j = 0; j < 4; ++j)
                    acc[i][j] += xv[i][0] * wr[0][j] + xv[i][1] * wr[1][j]
                               + xv[i][2] * wr[2][j] + xv[i][3] * wr[3][j];
        }
        __syncthreads();
    }

    const float QSCALE = 0.18033688011112042f;   // 0.125 * log2(e)
    const f4 bias4 = *(const f4*)&bs[n0 + tx * 4];
    #pragma unroll
    for (int i = 0; i < 4; ++i) {
        const int m = m0 + ty * 4 + i;
        const int bidx = m >> 12;
        const int s = m & 4095;
        #pragma unroll
        for (int j = 0; j < 4; ++j) {
            const int n = n0 + tx * 4 + j;
            const int hh = n >> 6;
            const int dd = n & 63;
            float v = acc[i][j] + bias4[j];
            if (proj == 0) {
                v *= QSCALE;
                qb[(((size_t)bidx * NH + hh) * SS + s) * KP + dd] = __float2bfloat16(v);
            } else if (proj == 1) {
                kb[(((size_t)bidx * NH + hh) * SS + s) * KP + dd] = __float2bfloat16(v);
            } else {
                vtb[(((size_t)bidx * NH + hh) * HD + dd) * SS + s] = __float2bfloat16(v);
            }
        }
    }

    // ---- augmentation dims 64..95: group onehot (q: beta*log2e, k: 1.0)
    if ((nt & 3) == 0 && proj < 2) {
        const float bl2e = *betaP;
        const int r = tid >> 2, hh = tid & 3;   // 64 rows x 4 heads
        const int m = m0 + r;
        const int bidx = m >> 12;
        const int s = m & 4095;
        const int cg = gid[codons[bidx * SS + s] & 63];
        __hip_bfloat16* dst = (proj == 0 ? qb : kb)
                              + (((size_t)(bidx * NH + hh) * SS + s) * KP + 64);
        const bf8 z = {0, 0, 0, 0, 0, 0, 0, 0};
        #pragma unroll
        for (int j = 0; j < 4; ++j) *(bf8*)&dst[j * 8] = z;
        dst[cg] = __float2bfloat16(proj == 0 ? bl2e : 1.0f);
    }
}

// ---------------------------------------------------------------------------
// Flash attention: barrier-free independent warps, operands direct from
// global (K/V is L2-resident per head; bh = bid&7 pins each head to an XCD).
// Block = 4 warps = 4 KV-quarters of ONE 32-row q-tile; end-merge via LDS.
// No-max exp2 softmax -> partials are directly summable.
// ---------------------------------------------------------------------------
__global__ __launch_bounds__(256, 3)
void attn_kernel(const __hip_bfloat16* __restrict__ qg,
                 const __hip_bfloat16* __restrict__ kg,
                 const __hip_bfloat16* __restrict__ vtg,
                 float* __restrict__ aout)
{
    const int bid = blockIdx.x;           // 1024 blocks
    const int bh = bid & 7;               // XCD-pinned head
    const int b = bh >> 2, h = bh & 3;
    const int qtile = bid >> 3;           // 0..127
    const int tid = threadIdx.x;
    const int w = tid >> 6;               // KV quarter 0..3
    const int lane = tid & 63;
    const int q5 = lane & 31;
    const int hi = lane >> 5;

    __shared__ float o_sh[4][32][69];     // per-quarter partial O (pitch 69: conflict-free)
    __shared__ float l_sh[4][32];

    const size_t kbase  = (size_t)(b * NH + h) * SS * KP;
    const size_t vtbase = (size_t)(b * NH + h) * HD * SS;
    const int qrow = qtile * 32 + q5;

    // ---- Q fragments (B operand), 96 dims
    const size_t qoff = ((size_t)(b * NH + h) * SS + qrow) * KP;
    bf8 qf[6];
    #pragma unroll
    for (int ks = 0; ks < 6; ++ks)
        qf[ks] = *(const bf8*)&qg[qoff + ks * 16 + hi * 8];

    f16v oacc0, oacc1;
    #pragma unroll
    for (int r = 0; r < 16; ++r) { oacc0[r] = 0.0f; oacc1[r] = 0.0f; }
    float lrun = 0.0f;

    for (int t = 0; t < 16; ++t) {
        const int kv0 = w * 1024 + t * 64;

        // ---- K fragments direct from global (A operand rows = keys)
        const __hip_bfloat16* kR0 = &kg[kbase + (size_t)(kv0 + q5) * KP + hi * 8];
        const __hip_bfloat16* kR1 = kR0 + 32 * KP;
        bf8 kf0[6], kf1[6];
        #pragma unroll
        for (int ks = 0; ks < 6; ++ks) {
            kf0[ks] = *(const bf8*)&kR0[ks * 16];
            kf1[ks] = *(const bf8*)&kR1[ks * 16];
        }

        f16v sA, sB;
        #pragma unroll
        for (int r = 0; r < 16; ++r) { sA[r] = 0.0f; sB[r] = 0.0f; }
        __builtin_amdgcn_s_setprio(1);
        #pragma unroll
        for (int ks = 0; ks < 6; ++ks) {
            sA = __builtin_amdgcn_mfma_f32_32x32x16_bf16(kf0[ks], qf[ks], sA, 0, 0, 0);
            sB = __builtin_amdgcn_mfma_f32_32x32x16_bf16(kf1[ks], qf[ks], sB, 0, 0, 0);
        }
        __builtin_amdgcn_s_setprio(0);

        // ---- V fragments for this tile (issue early, consume after pack)
        const __hip_bfloat16* vR0 = &vtg[vtbase + (size_t)q5 * SS + kv0 + hi * 8];
        const __hip_bfloat16* vR1 = vR0 + (size_t)32 * SS;
        bf8 vf0[4], vf1[4];
        #pragma unroll
        for (int ks = 0; ks < 4; ++ks) {
            vf0[ks] = *(const bf8*)&vR0[ks * 16];
            vf1[ks] = *(const bf8*)&vR1[ks * 16];
        }

        // ---- p = 2^s (no max subtraction; fp32 range is ample)
        float ls = 0.0f;
        #pragma unroll
        for (int r = 0; r < 16; ++r) { sA[r] = fast_exp2(sA[r]); ls += sA[r]; }
        #pragma unroll
        for (int r = 0; r < 16; ++r) { sB[r] = fast_exp2(sB[r]); ls += sB[r]; }
        lrun += ls;

        // ---- P -> bf16 dwords; exchange halves to build PV B-fragments
        unsigned dwv[2][4][2];
        #pragma unroll
        for (int j = 0; j < 4; ++j)
            #pragma unroll
            for (int c = 0; c < 2; ++c) {
                dwv[0][j][c] = pack2(sA[j * 4 + 2 * c], sA[j * 4 + 2 * c + 1]);
                dwv[1][j][c] = pack2(sB[j * 4 + 2 * c], sB[j * 4 + 2 * c + 1]);
            }
        unsigned rc[2][2][2];
        #pragma unroll
        for (int t2 = 0; t2 < 2; ++t2)
            #pragma unroll
            for (int k1 = 0; k1 < 2; ++k1)
                #pragma unroll
                for (int c = 0; c < 2; ++c) {
                    const unsigned snd = hi ? dwv[t2][2 * k1][c] : dwv[t2][2 * k1 + 1][c];
                    rc[t2][k1][c] = (unsigned)__shfl_xor((int)snd, 32, 64);
                }

        // ---- PV: D[d][q], A = V^T frag, B = P frag
        __builtin_amdgcn_s_setprio(1);
        #pragma unroll
        for (int ks = 0; ks < 4; ++ks) {
            const int t2 = ks >> 1, k1 = ks & 1;
            union { unsigned u[4]; bf8 v; } pf;
            pf.u[0] = hi ? rc[t2][k1][0] : dwv[t2][2 * k1][0];
            pf.u[1] = hi ? rc[t2][k1][1] : dwv[t2][2 * k1][1];
            pf.u[2] = hi ? dwv[t2][2 * k1 + 1][0] : rc[t2][k1][0];
            pf.u[3] = hi ? dwv[t2][2 * k1 + 1][1] : rc[t2][k1][1];
            oacc0 = __builtin_amdgcn_mfma_f32_32x32x16_bf16(vf0[ks], pf.v, oacc0, 0, 0, 0);
            oacc1 = __builtin_amdgcn_mfma_f32_32x32x16_bf16(vf1[ks], pf.v, oacc1, 0, 0, 0);
        }
        __builtin_amdgcn_s_setprio(0);
    }

    // ---- per-warp partial -> LDS
    const float ltot = lrun + __shfl_xor(lrun, 32, 64);
    #pragma unroll
    for (int r = 0; r < 16; ++r) {
        const int d = (r & 3) + 8 * (r >> 2) + 4 * hi;
        o_sh[w][q5][d] = oacc0[r];
        o_sh[w][q5][32 + d] = oacc1[r];
    }
    if (hi == 0) l_sh[w][q5] = ltot;
    __syncthreads();

    // ---- cooperative merge: 256 threads over 32 rows x 64 dims
    const int row = tid >> 3;
    const int d0 = (tid & 7) * 8;
    const float inv = 1.0f / (l_sh[0][row] + l_sh[1][row] + l_sh[2][row] + l_sh[3][row]);
    float vals[8];
    #pragma unroll
    for (int j = 0; j < 8; ++j)
        vals[j] = (o_sh[0][row][d0 + j] + o_sh[1][row][d0 + j]
                 + o_sh[2][row][d0 + j] + o_sh[3][row][d0 + j]) * inv;
    f4 v0, v1;
    #pragma unroll
    for (int j = 0; j < 4; ++j) { v0[j] = vals[j]; v1[j] = vals[4 + j]; }
    float* dst = &aout[((size_t)b * SS + qtile * 32 + row) * HID + h * HD + d0];
    *(f4*)&dst[0] = v0;
    *(f4*)&dst[4] = v1;
}

// ---------------------------------------------------------------------------
// Output projection: A(8192x256) @ Wo^T + bo -> out fp32. grid (4, 128).
// ---------------------------------------------------------------------------
__global__ __launch_bounds__(256)
void out_proj_kernel(const float* __restrict__ a, const float* __restrict__ wo,
                     const float* __restrict__ bo, float* __restrict__ out)
{
    const int n0 = blockIdx.x * 64;
    const int m0 = blockIdx.y * 64;

    __shared__ __align__(16) float xs[64][68];
    __shared__ __align__(16) float wt[64][64];

    const int tid = threadIdx.x;
    const int tx = tid & 15, ty = tid >> 4;

    float acc[4][4] = {};

    for (int k0 = 0; k0 < 256; k0 += 64) {
        {
            const int c4 = (tid & 15) * 4;
            const int r0 = tid >> 4;
            #pragma unroll
            for (int p = 0; p < 4; ++p) {
                const int r = r0 + p * 16;
                *(f4*)&xs[r][c4] = *(const f4*)&a[(size_t)(m0 + r) * HID + k0 + c4];
            }
        }
        {
            const int col = tid & 63;
            const int kb4 = (tid >> 6) * 16;
            #pragma unroll
            for (int kk = 0; kk < 16; kk += 4) {
                f4 v = *(const f4*)&wo[(size_t)(n0 + col) * HID + k0 + kb4 + kk];
                wt[kb4 + kk + 0][col] = v[0];
                wt[kb4 + kk + 1][col] = v[1];
                wt[kb4 + kk + 2][col] = v[2];
                wt[kb4 + kk + 3][col] = v[3];
            }
        }
        __syncthreads();

        for (int kk = 0; kk < 64; kk += 4) {
            f4 xv[4], wr[4];
            #pragma unroll
            for (int i = 0; i < 4; ++i) xv[i] = *(const f4*)&xs[ty * 4 + i][kk];
            #pragma unroll
            for (int t = 0; t < 4; ++t) wr[t] = *(const f4*)&wt[kk + t][tx * 4];
            #pragma unroll
            for (int i = 0; i < 4; ++i)
                #pragma unroll
                for (int j = 0; j < 4; ++j)
                    acc[i][j] += xv[i][0] * wr[0][j] + xv[i][1] * wr[1][j]
                               + xv[i][2] * wr[2][j] + xv[i][3] * wr[3][j];
        }
        __syncthreads();
    }

    const f4 bias4 = *(const f4*)&bo[n0 + tx * 4];
    #pragma unroll
    for (int i = 0; i < 4; ++i) {
        const int m = m0 + ty * 4 + i;
        f4 v;
        #pragma unroll
        for (int j = 0; j < 4; ++j) v[j] = acc[i][j] + bias4[j];
        *(f4*)&out[(size_t)m * HID + n0 + tx * 4] = v;
    }
}

extern "C" void kernel_launch(void* const* d_in, const int* in_sizes, int n_in,
                              void* d_out, int out_size, void* d_ws, size_t ws_size,
                              hipStream_t stream)
{
    (void)in_sizes; (void)n_in; (void)out_size; (void)ws_size;
    const float* x        = (const float*)d_in[0];
    const int*   codons   = (const int*)d_in[1];
    const float* syn_bias = (const float*)d_in[2];
    const float* wq = (const float*)d_in[3];
    const float* bq = (const float*)d_in[4];
    const float* wk = (const float*)d_in[5];
    const float* bk = (const float*)d_in[6];
    const float* wv = (const float*)d_in[7];
    const float* bv = (const float*)d_in[8];
    const float* wo = (const float*)d_in[9];
    const float* bo = (const float*)d_in[10];
    float* out = (float*)d_out;

    char* ws = (char*)d_ws;
    int*   gid   = (int*)(ws);                       // 256 B
    float* betaP = (float*)(ws + 256);               // 4 B
    __hip_bfloat16* qb  = (__hip_bfloat16*)(ws + (size_t)(1u << 20));       // 6.29 MB
    __hip_bfloat16* kb  = (__hip_bfloat16*)(ws + (size_t)7340032u);         // 6.29 MB
    __hip_bfloat16* vtb = (__hip_bfloat16*)(ws + (size_t)13631488u);        // 4 MB
    float* aout         = (float*)(ws + (size_t)17825792u);                 // 8 MB

    setup_kernel<<<1, 64, 0, stream>>>(syn_bias, gid, betaP);
    qkv_proj_kernel<<<dim3(12, 128), 256, 0, stream>>>(x, wq, bq, wk, bk, wv, bv,
                                                       codons, gid, betaP, qb, kb, vtb);
    attn_kernel<<<1024, 256, 0, stream>>>(qb, kb, vtb, aout);
    out_proj_kernel<<<dim3(4, 128), 256, 0, stream>>>(aout, wo, bo, out);
}

// Round 5
// 209.362 us; speedup vs baseline: 1.2950x; 1.1688x over previous
//
#include <hip/hip_runtime.h>
#include <hip/hip_bf16.h>

#define NH 4
#define HD 64
#define HID 256
#define SS 4096
#define KP 96   // augmented Q/K dims (64 head dims + 32 group-onehot dims)

// fragment-major sizes per (b,h)
#define KFRAG_PER_HEAD (64 * 12 * 64 * 8)   // 393216 elems = 4096*96
#define VFRAG_PER_HEAD (64 * 8 * 64 * 8)    // 262144 elems = 4096*64

typedef float f4 __attribute__((ext_vector_type(4)));
typedef float f16v __attribute__((ext_vector_type(16)));
typedef short bf8 __attribute__((ext_vector_type(8)));   // 8 bf16 (4 VGPRs)
typedef short bf4 __attribute__((ext_vector_type(4)));   // 4 bf16 (8B)

static __device__ __forceinline__ float fast_exp2(float x) {
#if __has_builtin(__builtin_amdgcn_exp2f)
    return __builtin_amdgcn_exp2f(x);
#else
    float r; asm("v_exp_f32 %0, %1" : "=v"(r) : "v"(x)); return r;
#endif
}

static __device__ __forceinline__ unsigned pack2(float a, float b) {
    unsigned ua = (unsigned)__bfloat16_as_ushort(__float2bfloat16(a));
    unsigned ub = (unsigned)__bfloat16_as_ushort(__float2bfloat16(b));
    return ua | (ub << 16);
}

// ---------------------------------------------------------------------------
// Setup: codon->group-id map + beta*log2e, from the synonymy matrix.
// ---------------------------------------------------------------------------
__global__ void setup_kernel(const float* __restrict__ syn,
                             int* __restrict__ gid, float* __restrict__ betaP)
{
    const int lane = threadIdx.x;          // 0..63
    int rep = 64;
    for (int j = 63; j >= 0; --j)
        if (syn[lane * 64 + j] != 0.0f) rep = j;   // first nonzero = group min
    if (rep == 64) rep = lane;
    unsigned long long m = __ballot(rep == lane);  // group representatives
    int id = (int)__popcll(m & ((2ull << rep) - 1ull)) - 1;
    if (id < 0) id = 0;
    gid[lane] = id;                                 // 0..20 (<=31)
    if (lane == 0) *betaP = syn[0] * 1.44269504088896f;  // diag = beta
}

// ---------------------------------------------------------------------------
// QKV projection: X(8192x256) @ W^T + b.
// q: row-major bf16 [b][h][s][96], scaled by 0.125*log2e, aug dims onehot.
// k: FRAGMENT-major bf16 per head: [t64][j12][lane64][8]  (j = (d>>4)*2 +
//    ((s>>5)&1); lane = ((d>>3)&1)*32 + (s&31); elem = d&7)
// v: FRAGMENT-major bf16 per head: [t64][j8][lane64][8]   (j = ((s>>4)&3)*2 +
//    (d>>5); lane = (d&31) + ((s>>3)&1)*32; elem = s&7)
// ---------------------------------------------------------------------------
__global__ __launch_bounds__(256)
void qkv_proj_kernel(const float* __restrict__ x,
                     const float* __restrict__ wq, const float* __restrict__ bq,
                     const float* __restrict__ wk, const float* __restrict__ bk,
                     const float* __restrict__ wv, const float* __restrict__ bv,
                     const int* __restrict__ codons,
                     const int* __restrict__ gid, const float* __restrict__ betaP,
                     __hip_bfloat16* __restrict__ qb,
                     __hip_bfloat16* __restrict__ kb,
                     __hip_bfloat16* __restrict__ vtb)
{
    const int nt = blockIdx.x;            // 0..11
    const int m0 = blockIdx.y * 64;       // row tile
    const int proj = nt >> 2;             // 0=q 1=k 2=v
    const int n0 = (nt & 3) * 64;         // col within projection
    const float* __restrict__ w  = (proj == 0) ? wq : (proj == 1) ? wk : wv;
    const float* __restrict__ bs = (proj == 0) ? bq : (proj == 1) ? bk : bv;

    __shared__ __align__(16) float xs[64][68];
    __shared__ __align__(16) float wt[64][64];

    const int tid = threadIdx.x;
    const int tx = tid & 15, ty = tid >> 4;

    float acc[4][4] = {};

    for (int k0 = 0; k0 < 256; k0 += 64) {
        {
            const int c4 = (tid & 15) * 4;
            const int r0 = tid >> 4;
            #pragma unroll
            for (int p = 0; p < 4; ++p) {
                const int r = r0 + p * 16;
                *(f4*)&xs[r][c4] = *(const f4*)&x[(size_t)(m0 + r) * HID + k0 + c4];
            }
        }
        {
            const int col = tid & 63;
            const int kb4 = (tid >> 6) * 16;
            #pragma unroll
            for (int kk = 0; kk < 16; kk += 4) {
                f4 v = *(const f4*)&w[(size_t)(n0 + col) * HID + k0 + kb4 + kk];
                wt[kb4 + kk + 0][col] = v[0];
                wt[kb4 + kk + 1][col] = v[1];
                wt[kb4 + kk + 2][col] = v[2];
                wt[kb4 + kk + 3][col] = v[3];
            }
        }
        __syncthreads();

        for (int kk = 0; kk < 64; kk += 4) {
            f4 xv[4], wr[4];
            #pragma unroll
            for (int i = 0; i < 4; ++i) xv[i] = *(const f4*)&xs[ty * 4 + i][kk];
            #pragma unroll
            for (int t = 0; t < 4; ++t) wr[t] = *(const f4*)&wt[kk + t][tx * 4];
            #pragma unroll
            for (int i = 0; i < 4; ++i)
                #pragma unroll
                for (int j = 0; j < 4; ++j)
                    acc[i][j] += xv[i][0] * wr[0][j] + xv[i][1] * wr[1][j]
                               + xv[i][2] * wr[2][j] + xv[i][3] * wr[3][j];
        }
        __syncthreads();
    }

    const float QSCALE = 0.18033688011112042f;   // 0.125 * log2(e)
    const f4 bias4 = *(const f4*)&bs[n0 + tx * 4];
    #pragma unroll
    for (int i = 0; i < 4; ++i) {
        const int m = m0 + ty * 4 + i;
        const int bidx = m >> 12;
        const int s = m & 4095;
        const int hh = (n0 + tx * 4) >> 6;
        const int dd0 = (n0 + tx * 4) & 63;      // within-head dim base
        if (proj == 0) {
            #pragma unroll
            for (int j = 0; j < 4; ++j) {
                float v = (acc[i][j] + bias4[j]) * QSCALE;
                qb[(((size_t)bidx * NH + hh) * SS + s) * KP + dd0 + j] = __float2bfloat16(v);
            }
        } else if (proj == 1) {
            // K fragment-major: one 8B store of 4 bf16
            bf4 kv4;
            #pragma unroll
            for (int j = 0; j < 4; ++j)
                kv4[j] = (short)__bfloat16_as_ushort(__float2bfloat16(acc[i][j] + bias4[j]));
            const int t = s >> 6;
            const int jf = (dd0 >> 4) * 2 + ((s >> 5) & 1);
            const int lane = ((dd0 >> 3) & 1) * 32 + (s & 31);
            const int elem = dd0 & 7;            // 0 or 4
            __hip_bfloat16* base = kb + (size_t)(bidx * NH + hh) * KFRAG_PER_HEAD;
            *(bf4*)&base[((size_t)(t * 12 + jf) * 64 + lane) * 8 + elem] = kv4;
        } else {
            // V fragment-major: 4 scalar stores (lane varies)
            const int t = s >> 6;
            const int jf = ((s >> 4) & 3) * 2 + (dd0 >> 5);
            const int elem = s & 7;
            __hip_bfloat16* base = vtb + (size_t)(bidx * NH + hh) * VFRAG_PER_HEAD;
            #pragma unroll
            for (int j = 0; j < 4; ++j) {
                const int dd = dd0 + j;
                const int lane = (dd & 31) + ((s >> 3) & 1) * 32;
                base[((size_t)(t * 8 + jf) * 64 + lane) * 8 + elem] =
                    __float2bfloat16(acc[i][j] + bias4[j]);
            }
        }
    }

    // ---- augmentation dims 64..95: group onehot (q: beta*log2e, k: 1.0)
    if ((nt & 3) == 0 && proj < 2) {
        const float bl2e = *betaP;
        const int r = tid >> 2, hh = tid & 3;   // 64 rows x 4 heads
        const int m = m0 + r;
        const int bidx = m >> 12;
        const int s = m & 4095;
        const int cg = gid[codons[bidx * SS + s] & 63];
        const bf8 z = {0, 0, 0, 0, 0, 0, 0, 0};
        if (proj == 0) {
            __hip_bfloat16* dst = qb + (((size_t)(bidx * NH + hh) * SS + s) * KP + 64);
            #pragma unroll
            for (int j = 0; j < 4; ++j) *(bf8*)&dst[j * 8] = z;
            dst[cg] = __float2bfloat16(bl2e);
        } else {
            const int t = s >> 6;
            const int hs = (s >> 5) & 1;
            __hip_bfloat16* base = kb + (size_t)(bidx * NH + hh) * KFRAG_PER_HEAD;
            // zero the 4 aug fragment slots for this key
            *(bf8*)&base[((size_t)(t * 12 + 8 + hs) * 64 + (s & 31)) * 8] = z;
            *(bf8*)&base[((size_t)(t * 12 + 8 + hs) * 64 + 32 + (s & 31)) * 8] = z;
            *(bf8*)&base[((size_t)(t * 12 + 10 + hs) * 64 + (s & 31)) * 8] = z;
            *(bf8*)&base[((size_t)(t * 12 + 10 + hs) * 64 + 32 + (s & 31)) * 8] = z;
            // onehot
            const int jf = 8 + (cg >> 4) * 2 + hs;
            const int lane = ((cg >> 3) & 1) * 32 + (s & 31);
            base[((size_t)(t * 12 + jf) * 64 + lane) * 8 + (cg & 7)] = __float2bfloat16(1.0f);
        }
    }
}

// ---------------------------------------------------------------------------
// Flash attention: barrier-free warps, fragment-major K/V -> every load is a
// fully coalesced 1KB wave-load. K double-buffered across iterations.
// Block = 4 warps = 4 KV-quarters of ONE 32-row q-tile; end-merge via LDS.
// ---------------------------------------------------------------------------
__global__ __launch_bounds__(256, 2)
void attn_kernel(const __hip_bfloat16* __restrict__ qg,
                 const __hip_bfloat16* __restrict__ kfrag,
                 const __hip_bfloat16* __restrict__ vfrag,
                 float* __restrict__ aout)
{
    const int bid = blockIdx.x;           // 1024 blocks
    const int bh = bid & 7;               // XCD-pinned head
    const int b = bh >> 2, h = bh & 3;
    const int qtile = bid >> 3;           // 0..127
    const int tid = threadIdx.x;
    const int w = tid >> 6;               // KV quarter 0..3
    const int lane = tid & 63;
    const int q5 = lane & 31;
    const int hi = lane >> 5;

    __shared__ float o_sh[4][32][69];
    __shared__ float l_sh[4][32];

    const __hip_bfloat16* kf_base = kfrag + (size_t)(b * NH + h) * KFRAG_PER_HEAD + lane * 8;
    const __hip_bfloat16* vf_base = vfrag + (size_t)(b * NH + h) * VFRAG_PER_HEAD + lane * 8;
    const int qrow = qtile * 32 + q5;

    // ---- Q fragments (B operand), 96 dims, row-major (one-time load)
    const size_t qoff = ((size_t)(b * NH + h) * SS + qrow) * KP;
    bf8 qf[6];
    #pragma unroll
    for (int ks = 0; ks < 6; ++ks)
        qf[ks] = *(const bf8*)&qg[qoff + ks * 16 + hi * 8];

    f16v oacc0, oacc1;
    #pragma unroll
    for (int r = 0; r < 16; ++r) { oacc0[r] = 0.0f; oacc1[r] = 0.0f; }
    float lrun = 0.0f;

    bf8 kA[12], kB[12];

    auto loadK = [&](bf8 (&dst)[12], int tt) {
        const __hip_bfloat16* p = kf_base + (size_t)tt * (12 * 64 * 8);
        #pragma unroll
        for (int j = 0; j < 12; ++j) dst[j] = *(const bf8*)&p[j * 512];
    };

    auto step = [&](bf8 (&kf)[12], bf8 (&kn)[12], int tt, bool pf) {
        // V fragments for this tile (consumed late; issued first)
        bf8 vf[8];
        const __hip_bfloat16* vp = vf_base + (size_t)tt * (8 * 64 * 8);
        #pragma unroll
        for (int j = 0; j < 8; ++j) vf[j] = *(const bf8*)&vp[j * 512];
        // prefetch next K tile
        if (pf) loadK(kn, tt + 1);

        // ---- QK^T (swapped): D[key][q]
        f16v sA, sB;
        #pragma unroll
        for (int r = 0; r < 16; ++r) { sA[r] = 0.0f; sB[r] = 0.0f; }
        __builtin_amdgcn_s_setprio(1);
        #pragma unroll
        for (int ks = 0; ks < 6; ++ks) {
            sA = __builtin_amdgcn_mfma_f32_32x32x16_bf16(kf[ks * 2 + 0], qf[ks], sA, 0, 0, 0);
            sB = __builtin_amdgcn_mfma_f32_32x32x16_bf16(kf[ks * 2 + 1], qf[ks], sB, 0, 0, 0);
        }
        __builtin_amdgcn_s_setprio(0);

        // ---- p = 2^s (no max subtraction; fp32 range is ample)
        float ls = 0.0f;
        #pragma unroll
        for (int r = 0; r < 16; ++r) { sA[r] = fast_exp2(sA[r]); ls += sA[r]; }
        #pragma unroll
        for (int r = 0; r < 16; ++r) { sB[r] = fast_exp2(sB[r]); ls += sB[r]; }
        lrun += ls;

        // ---- P -> bf16 dwords; exchange halves to build PV B-fragments
        unsigned dwv[2][4][2];
        #pragma unroll
        for (int j = 0; j < 4; ++j)
            #pragma unroll
            for (int c = 0; c < 2; ++c) {
                dwv[0][j][c] = pack2(sA[j * 4 + 2 * c], sA[j * 4 + 2 * c + 1]);
                dwv[1][j][c] = pack2(sB[j * 4 + 2 * c], sB[j * 4 + 2 * c + 1]);
            }
        unsigned rc[2][2][2];
        #pragma unroll
        for (int t2 = 0; t2 < 2; ++t2)
            #pragma unroll
            for (int k1 = 0; k1 < 2; ++k1)
                #pragma unroll
                for (int c = 0; c < 2; ++c) {
                    const unsigned snd = hi ? dwv[t2][2 * k1][c] : dwv[t2][2 * k1 + 1][c];
                    rc[t2][k1][c] = (unsigned)__shfl_xor((int)snd, 32, 64);
                }

        // ---- PV: D[d][q], A = V^T frag, B = P frag
        __builtin_amdgcn_s_setprio(1);
        #pragma unroll
        for (int ks = 0; ks < 4; ++ks) {
            const int t2 = ks >> 1, k1 = ks & 1;
            union { unsigned u[4]; bf8 v; } pfv;
            pfv.u[0] = hi ? rc[t2][k1][0] : dwv[t2][2 * k1][0];
            pfv.u[1] = hi ? rc[t2][k1][1] : dwv[t2][2 * k1][1];
            pfv.u[2] = hi ? dwv[t2][2 * k1 + 1][0] : rc[t2][k1][0];
            pfv.u[3] = hi ? dwv[t2][2 * k1 + 1][1] : rc[t2][k1][1];
            oacc0 = __builtin_amdgcn_mfma_f32_32x32x16_bf16(vf[ks * 2 + 0], pfv.v, oacc0, 0, 0, 0);
            oacc1 = __builtin_amdgcn_mfma_f32_32x32x16_bf16(vf[ks * 2 + 1], pfv.v, oacc1, 0, 0, 0);
        }
        __builtin_amdgcn_s_setprio(0);
    };

    const int tt0 = w * 16;
    loadK(kA, tt0);
    #pragma unroll 1
    for (int t = 0; t < 16; t += 2) {
        step(kA, kB, tt0 + t, true);
        step(kB, kA, tt0 + t + 1, t + 2 < 16);
    }

    // ---- per-warp partial -> LDS
    const float ltot = lrun + __shfl_xor(lrun, 32, 64);
    #pragma unroll
    for (int r = 0; r < 16; ++r) {
        const int d = (r & 3) + 8 * (r >> 2) + 4 * hi;
        o_sh[w][q5][d] = oacc0[r];
        o_sh[w][q5][32 + d] = oacc1[r];
    }
    if (hi == 0) l_sh[w][q5] = ltot;
    __syncthreads();

    // ---- cooperative merge: 256 threads over 32 rows x 64 dims
    const int row = tid >> 3;
    const int d0 = (tid & 7) * 8;
    const float inv = 1.0f / (l_sh[0][row] + l_sh[1][row] + l_sh[2][row] + l_sh[3][row]);
    float vals[8];
    #pragma unroll
    for (int j = 0; j < 8; ++j)
        vals[j] = (o_sh[0][row][d0 + j] + o_sh[1][row][d0 + j]
                 + o_sh[2][row][d0 + j] + o_sh[3][row][d0 + j]) * inv;
    f4 v0, v1;
    #pragma unroll
    for (int j = 0; j < 4; ++j) { v0[j] = vals[j]; v1[j] = vals[4 + j]; }
    float* dst = &aout[((size_t)b * SS + qtile * 32 + row) * HID + h * HD + d0];
    *(f4*)&dst[0] = v0;
    *(f4*)&dst[4] = v1;
}

// ---------------------------------------------------------------------------
// Output projection: A(8192x256) @ Wo^T + bo -> out fp32. grid (4, 128).
// ---------------------------------------------------------------------------
__global__ __launch_bounds__(256)
void out_proj_kernel(const float* __restrict__ a, const float* __restrict__ wo,
                     const float* __restrict__ bo, float* __restrict__ out)
{
    const int n0 = blockIdx.x * 64;
    const int m0 = blockIdx.y * 64;

    __shared__ __align__(16) float xs[64][68];
    __shared__ __align__(16) float wt[64][64];

    const int tid = threadIdx.x;
    const int tx = tid & 15, ty = tid >> 4;

    float acc[4][4] = {};

    for (int k0 = 0; k0 < 256; k0 += 64) {
        {
            const int c4 = (tid & 15) * 4;
            const int r0 = tid >> 4;
            #pragma unroll
            for (int p = 0; p < 4; ++p) {
                const int r = r0 + p * 16;
                *(f4*)&xs[r][c4] = *(const f4*)&a[(size_t)(m0 + r) * HID + k0 + c4];
            }
        }
        {
            const int col = tid & 63;
            const int kb4 = (tid >> 6) * 16;
            #pragma unroll
            for (int kk = 0; kk < 16; kk += 4) {
                f4 v = *(const f4*)&wo[(size_t)(n0 + col) * HID + k0 + kb4 + kk];
                wt[kb4 + kk + 0][col] = v[0];
                wt[kb4 + kk + 1][col] = v[1];
                wt[kb4 + kk + 2][col] = v[2];
                wt[kb4 + kk + 3][col] = v[3];
            }
        }
        __syncthreads();

        for (int kk = 0; kk < 64; kk += 4) {
            f4 xv[4], wr[4];
            #pragma unroll
            for (int i = 0; i < 4; ++i) xv[i] = *(const f4*)&xs[ty * 4 + i][kk];
            #pragma unroll
            for (int t = 0; t < 4; ++t) wr[t] = *(const f4*)&wt[kk + t][tx * 4];
            #pragma unroll
            for (int i = 0; i < 4; ++i)
                #pragma unroll
                for (int j = 0; j < 4; ++j)
                    acc[i][j] += xv[i][0] * wr[0][j] + xv[i][1] * wr[1][j]
                               + xv[i][2] * wr[2][j] + xv[i][3] * wr[3][j];
        }
        __syncthreads();
    }

    const f4 bias4 = *(const f4*)&bo[n0 + tx * 4];
    #pragma unroll
    for (int i = 0; i < 4; ++i) {
        const int m = m0 + ty * 4 + i;
        f4 v;
        #pragma unroll
        for (int j = 0; j < 4; ++j) v[j] = acc[i][j] + bias4[j];
        *(f4*)&out[(size_t)m * HID + n0 + tx * 4] = v;
    }
}

extern "C" void kernel_launch(void* const* d_in, const int* in_sizes, int n_in,
                              void* d_out, int out_size, void* d_ws, size_t ws_size,
                              hipStream_t stream)
{
    (void)in_sizes; (void)n_in; (void)out_size; (void)ws_size;
    const float* x        = (const float*)d_in[0];
    const int*   codons   = (const int*)d_in[1];
    const float* syn_bias = (const float*)d_in[2];
    const float* wq = (const float*)d_in[3];
    const float* bq = (const float*)d_in[4];
    const float* wk = (const float*)d_in[5];
    const float* bk = (const float*)d_in[6];
    const float* wv = (const float*)d_in[7];
    const float* bv = (const float*)d_in[8];
    const float* wo = (const float*)d_in[9];
    const float* bo = (const float*)d_in[10];
    float* out = (float*)d_out;

    char* ws = (char*)d_ws;
    int*   gid   = (int*)(ws);                       // 256 B
    float* betaP = (float*)(ws + 256);               // 4 B
    __hip_bfloat16* qb  = (__hip_bfloat16*)(ws + (size_t)(1u << 20));       // 6.29 MB
    __hip_bfloat16* kb  = (__hip_bfloat16*)(ws + (size_t)7340032u);         // 6.29 MB
    __hip_bfloat16* vtb = (__hip_bfloat16*)(ws + (size_t)13631488u);        // 4 MB
    float* aout         = (float*)(ws + (size_t)17825792u);                 // 8 MB

    setup_kernel<<<1, 64, 0, stream>>>(syn_bias, gid, betaP);
    qkv_proj_kernel<<<dim3(12, 128), 256, 0, stream>>>(x, wq, bq, wk, bk, wv, bv,
                                                       codons, gid, betaP, qb, kb, vtb);
    attn_kernel<<<1024, 256, 0, stream>>>(qb, kb, vtb, aout);
    out_proj_kernel<<<dim3(4, 128), 256, 0, stream>>>(aout, wo, bo, out);
}

// Round 6
// 90.930 us; speedup vs baseline: 2.9817x; 2.3024x over previous
//
#include <hip/hip_runtime.h>
#include <hip/hip_bf16.h>

#define NH 4
#define HD 64
#define HID 256
#define SS 4096
#define KP 96

#define QFRAG_PER_HEAD (128 * 6 * 64 * 8)   // 393216 elems
#define KFRAG_PER_HEAD (64 * 12 * 64 * 8)   // 393216 elems
#define VFRAG_PER_HEAD (64 * 8 * 64 * 8)    // 262144 elems

typedef float f4 __attribute__((ext_vector_type(4)));
typedef float f16v __attribute__((ext_vector_type(16)));
typedef short bf8 __attribute__((ext_vector_type(8)));   // 8 bf16
typedef unsigned int u4v __attribute__((ext_vector_type(4)));

static __device__ __forceinline__ float fast_exp2(float x) {
#if __has_builtin(__builtin_amdgcn_exp2f)
    return __builtin_amdgcn_exp2f(x);
#else
    float r; asm("v_exp_f32 %0, %1" : "=v"(r) : "v"(x)); return r;
#endif
}

static __device__ __forceinline__ unsigned pack2(float a, float b) {
    unsigned ua = (unsigned)__bfloat16_as_ushort(__float2bfloat16(a));
    unsigned ub = (unsigned)__bfloat16_as_ushort(__float2bfloat16(b));
    return ua | (ub << 16);
}

// ---------------------------------------------------------------------------
// Setup: codon->group-id map + beta*log2e.
// ---------------------------------------------------------------------------
__global__ void setup_kernel(const float* __restrict__ syn,
                             int* __restrict__ gid, float* __restrict__ betaP)
{
    const int lane = threadIdx.x;          // 0..63
    int rep = 64;
    for (int j = 63; j >= 0; --j)
        if (syn[lane * 64 + j] != 0.0f) rep = j;
    if (rep == 64) rep = lane;
    unsigned long long m = __ballot(rep == lane);
    int id = (int)__popcll(m & ((2ull << rep) - 1ull)) - 1;
    if (id < 0) id = 0;
    gid[lane] = id;                                 // 0..20
    if (lane == 0) *betaP = syn[0] * 1.44269504088896f;
}

// ---------------------------------------------------------------------------
// Pack wq/wk/wv/wo into MFMA fragment-major bf16:
// wpk[mat][dt8][ks16][lane64][8]: value = w[dt*32 + (lane&31)][ks*16 + (lane>>5)*8 + e]
// Works as both A-operand (row = lane&31) and B-operand (col = lane&31).
// ---------------------------------------------------------------------------
__global__ __launch_bounds__(256)
void pack_w_kernel(const float* __restrict__ wq, const float* __restrict__ wk,
                   const float* __restrict__ wv, const float* __restrict__ wo,
                   __hip_bfloat16* __restrict__ wpk)
{
    const int t = blockIdx.x * 256 + threadIdx.x;   // 0..32767
    const int mat = t >> 13;
    const int r = t & 8191;
    const int dt = r >> 10, ks = (r >> 6) & 15, lane = r & 63;
    const float* w = (mat == 0) ? wq : (mat == 1) ? wk : (mat == 2) ? wv : wo;
    const int row = dt * 32 + (lane & 31);
    const int col = ks * 16 + (lane >> 5) * 8;
    const f4 a = *(const f4*)&w[(size_t)row * 256 + col];
    const f4 b = *(const f4*)&w[(size_t)row * 256 + col + 4];
    union { unsigned u[4]; bf8 v; } o;
    o.u[0] = pack2(a[0], a[1]); o.u[1] = pack2(a[2], a[3]);
    o.u[2] = pack2(b[0], b[1]); o.u[3] = pack2(b[2], b[3]);
    *(bf8*)&wpk[(size_t)t * 8] = o.v;
}

// ---------------------------------------------------------------------------
// QKV projection via MFMA. grid 1536 = 256 stiles x 6 groups; block = 4 waves,
// each wave computes ONE 32x32 output tile (16 MFMA, K=256).
// q/k: operand-swapped (D lane = s, regs = d) -> pack-exchange -> frag stores.
// v: normal (D lane = d, regs = s) -> same exchange -> vfrag.
// ---------------------------------------------------------------------------
__global__ __launch_bounds__(256)
void qkv_mfma_kernel(const float* __restrict__ x,
                     const __hip_bfloat16* __restrict__ wpk,
                     const float* __restrict__ bq, const float* __restrict__ bk,
                     const float* __restrict__ bv,
                     const int* __restrict__ codons,
                     const int* __restrict__ gid, const float* __restrict__ betaP,
                     __hip_bfloat16* __restrict__ qfrag,
                     __hip_bfloat16* __restrict__ kfrag,
                     __hip_bfloat16* __restrict__ vfrag)
{
    const int bid = blockIdx.x;
    const int stile = bid / 6;            // 0..255 (32 rows each)
    const int grp = bid % 6;
    const int tid = threadIdx.x;
    const int w = tid >> 6, lane = tid & 63, hi = lane >> 5, l5 = lane & 31;

    const int bidx = stile >> 7;          // batch
    const int stl = stile & 127;          // s-tile within batch
    const int hs = stl & 1, tkv = stl >> 1;

    __shared__ __hip_bfloat16 xs[32][256];

    // ---- stage x tile fp32 -> bf16, chunk-swizzled (slot = c ^ row)
    {
        const int r0 = tid >> 5, c = tid & 31;
        #pragma unroll
        for (int it = 0; it < 4; ++it) {
            const int row = r0 + it * 8;
            const f4 a = *(const f4*)&x[(size_t)(stile * 32 + row) * HID + c * 8];
            const f4 b2 = *(const f4*)&x[(size_t)(stile * 32 + row) * HID + c * 8 + 4];
            union { unsigned u[4]; bf8 v; } o;
            o.u[0] = pack2(a[0], a[1]); o.u[1] = pack2(a[2], a[3]);
            o.u[2] = pack2(b2[0], b2[1]); o.u[3] = pack2(b2[2], b2[3]);
            *(bf8*)&xs[row][((c ^ row) & 31) * 8] = o.v;
        }
    }
    __syncthreads();

    // ---- tile job
    const int t24 = grp * 4 + w;          // 0..23
    const int mat = t24 >> 3;             // 0=q 1=k 2=v
    const int dt = t24 & 7;
    const int head = dt >> 1, d32 = dt & 1;

    const __hip_bfloat16* wb = wpk + (size_t)((mat * 8 + dt) * 16) * 512 + (size_t)lane * 8;
    bf8 wf[16];
    #pragma unroll
    for (int ks = 0; ks < 16; ++ks) wf[ks] = *(const bf8*)&wb[ks * 512];

    f16v acc;
    #pragma unroll
    for (int r = 0; r < 16; ++r) acc[r] = 0.0f;

    if (mat < 2) {
        #pragma unroll
        for (int ks = 0; ks < 16; ++ks) {
            const bf8 xf = *(const bf8*)&xs[l5][(((ks * 2 + hi) ^ l5) & 31) * 8];
            acc = __builtin_amdgcn_mfma_f32_32x32x16_bf16(wf[ks], xf, acc, 0, 0, 0);
        }
    } else {
        #pragma unroll
        for (int ks = 0; ks < 16; ++ks) {
            const bf8 xf = *(const bf8*)&xs[l5][(((ks * 2 + hi) ^ l5) & 31) * 8];
            acc = __builtin_amdgcn_mfma_f32_32x32x16_bf16(xf, wf[ks], acc, 0, 0, 0);
        }
    }

    // ---- bias (+ q scale)
    const float QSCALE = 0.18033688011112042f;   // 0.125 * log2(e)
    if (mat == 0) {
        f4 b4[4];
        #pragma unroll
        for (int j = 0; j < 4; ++j)
            b4[j] = *(const f4*)&bq[head * 64 + d32 * 32 + j * 8 + 4 * hi];
        #pragma unroll
        for (int r = 0; r < 16; ++r) acc[r] = (acc[r] + b4[r >> 2][r & 3]) * QSCALE;
    } else if (mat == 1) {
        f4 b4[4];
        #pragma unroll
        for (int j = 0; j < 4; ++j)
            b4[j] = *(const f4*)&bk[head * 64 + d32 * 32 + j * 8 + 4 * hi];
        #pragma unroll
        for (int r = 0; r < 16; ++r) acc[r] += b4[r >> 2][r & 3];
    } else {
        const float bn = bv[head * 64 + d32 * 32 + l5];
        #pragma unroll
        for (int r = 0; r < 16; ++r) acc[r] += bn;
    }

    // ---- pack-exchange (regs -> 8-elem fragment halves across hi)
    unsigned wd[8];
    #pragma unroll
    for (int i = 0; i < 8; ++i) wd[i] = pack2(acc[2 * i], acc[2 * i + 1]);
    const unsigned e0 = (unsigned)__shfl_xor((int)(hi ? wd[0] : wd[2]), 32, 64);
    const unsigned e1 = (unsigned)__shfl_xor((int)(hi ? wd[1] : wd[3]), 32, 64);
    const unsigned e2 = (unsigned)__shfl_xor((int)(hi ? wd[4] : wd[6]), 32, 64);
    const unsigned e3 = (unsigned)__shfl_xor((int)(hi ? wd[5] : wd[7]), 32, 64);
    union { unsigned u[4]; bf8 v; } fa, fb;
    if (hi == 0) {
        fa.u[0] = wd[0]; fa.u[1] = wd[1]; fa.u[2] = e0; fa.u[3] = e1;
        fb.u[0] = wd[4]; fb.u[1] = wd[5]; fb.u[2] = e2; fb.u[3] = e3;
    } else {
        fa.u[0] = e0; fa.u[1] = e1; fa.u[2] = wd[2]; fa.u[3] = wd[3];
        fb.u[0] = e2; fb.u[1] = e3; fb.u[2] = wd[6]; fb.u[3] = wd[7];
    }

    // ---- coalesced fragment stores
    const int hd = bidx * NH + head;
    if (mat == 0) {
        __hip_bfloat16* qb = qfrag + (size_t)hd * QFRAG_PER_HEAD;
        *(bf8*)&qb[((size_t)(stl * 6 + d32 * 2 + 0) * 64 + lane) * 8] = fa.v;
        *(bf8*)&qb[((size_t)(stl * 6 + d32 * 2 + 1) * 64 + lane) * 8] = fb.v;
    } else if (mat == 1) {
        __hip_bfloat16* kb = kfrag + (size_t)hd * KFRAG_PER_HEAD;
        *(bf8*)&kb[((size_t)(tkv * 12 + d32 * 4 + hs) * 64 + lane) * 8] = fa.v;
        *(bf8*)&kb[((size_t)(tkv * 12 + d32 * 4 + 2 + hs) * 64 + lane) * 8] = fb.v;
    } else {
        __hip_bfloat16* vb = vfrag + (size_t)hd * VFRAG_PER_HEAD;
        const int ja = ((stl * 2 + 0) & 3) * 2 + d32;
        const int jb = ((stl * 2 + 1) & 3) * 2 + d32;
        *(bf8*)&vb[((size_t)(tkv * 8 + ja) * 64 + lane) * 8] = fa.v;
        *(bf8*)&vb[((size_t)(tkv * 8 + jb) * 64 + lane) * 8] = fb.v;
    }

    // ---- augmentation dims (grp 0 blocks: wave w -> head w)
    if (grp == 0) {
        const int hh = w;
        const int hd2 = bidx * NH + hh;
        __hip_bfloat16* qb = qfrag + (size_t)hd2 * QFRAG_PER_HEAD;
        __hip_bfloat16* kb = kfrag + (size_t)hd2 * KFRAG_PER_HEAD;
        u4v z; z[0] = 0; z[1] = 0; z[2] = 0; z[3] = 0;
        *(u4v*)&qb[((size_t)(stl * 6 + 4) * 64 + lane) * 8] = z;
        *(u4v*)&qb[((size_t)(stl * 6 + 5) * 64 + lane) * 8] = z;
        *(u4v*)&kb[((size_t)(tkv * 12 + 8 + hs) * 64 + lane) * 8] = z;
        *(u4v*)&kb[((size_t)(tkv * 12 + 10 + hs) * 64 + lane) * 8] = z;
        asm volatile("s_waitcnt vmcnt(0)" ::: "memory");
        if (hi == 0) {
            const int cg = gid[codons[bidx * SS + stl * 32 + l5] & 63];
            const float bl2e = *betaP;
            const int lt = ((cg >> 3) & 1) * 32 + l5;
            qb[((size_t)(stl * 6 + 4 + (cg >> 4)) * 64 + lt) * 8 + (cg & 7)] =
                __float2bfloat16(bl2e);
            kb[((size_t)(tkv * 12 + 8 + (cg >> 4) * 2 + hs) * 64 + lt) * 8 + (cg & 7)] =
                __float2bfloat16(1.0f);
        }
    }
}

// ---------------------------------------------------------------------------
// Flash attention (unchanged structure from R5): barrier-free warps,
// fragment-major Q/K/V, coalesced 1KB wave-loads, K double-buffered.
// Epilogue now writes bf16 aout row-major.
// ---------------------------------------------------------------------------
__global__ __launch_bounds__(256, 2)
void attn_kernel(const __hip_bfloat16* __restrict__ qfrag,
                 const __hip_bfloat16* __restrict__ kfrag,
                 const __hip_bfloat16* __restrict__ vfrag,
                 __hip_bfloat16* __restrict__ aoutb)
{
    const int bid = blockIdx.x;           // 1024 blocks
    const int bh = bid & 7;
    const int b = bh >> 2, h = bh & 3;
    const int qtile = bid >> 3;           // 0..127
    const int tid = threadIdx.x;
    const int w = tid >> 6;               // KV quarter 0..3
    const int lane = tid & 63;
    const int q5 = lane & 31;
    const int hi = lane >> 5;

    __shared__ float o_sh[4][32][69];
    __shared__ float l_sh[4][32];

    const __hip_bfloat16* kf_base = kfrag + (size_t)(b * NH + h) * KFRAG_PER_HEAD + lane * 8;
    const __hip_bfloat16* vf_base = vfrag + (size_t)(b * NH + h) * VFRAG_PER_HEAD + lane * 8;

    // ---- Q fragments from qfrag (coalesced)
    const __hip_bfloat16* qb = qfrag + (size_t)(b * NH + h) * QFRAG_PER_HEAD
                               + ((size_t)qtile * 6 * 64 + lane) * 8;
    bf8 qf[6];
    #pragma unroll
    for (int ks = 0; ks < 6; ++ks)
        qf[ks] = *(const bf8*)&qb[ks * 512];

    f16v oacc0, oacc1;
    #pragma unroll
    for (int r = 0; r < 16; ++r) { oacc0[r] = 0.0f; oacc1[r] = 0.0f; }
    float lrun = 0.0f;

    bf8 kA[12], kB[12];

    auto loadK = [&](bf8 (&dst)[12], int tt) {
        const __hip_bfloat16* p = kf_base + (size_t)tt * (12 * 64 * 8);
        #pragma unroll
        for (int j = 0; j < 12; ++j) dst[j] = *(const bf8*)&p[j * 512];
    };

    auto step = [&](bf8 (&kf)[12], bf8 (&kn)[12], int tt, bool pf) {
        bf8 vf[8];
        const __hip_bfloat16* vp = vf_base + (size_t)tt * (8 * 64 * 8);
        #pragma unroll
        for (int j = 0; j < 8; ++j) vf[j] = *(const bf8*)&vp[j * 512];
        if (pf) loadK(kn, tt + 1);

        f16v sA, sB;
        #pragma unroll
        for (int r = 0; r < 16; ++r) { sA[r] = 0.0f; sB[r] = 0.0f; }
        __builtin_amdgcn_s_setprio(1);
        #pragma unroll
        for (int ks = 0; ks < 6; ++ks) {
            sA = __builtin_amdgcn_mfma_f32_32x32x16_bf16(kf[ks * 2 + 0], qf[ks], sA, 0, 0, 0);
            sB = __builtin_amdgcn_mfma_f32_32x32x16_bf16(kf[ks * 2 + 1], qf[ks], sB, 0, 0, 0);
        }
        __builtin_amdgcn_s_setprio(0);

        float ls = 0.0f;
        #pragma unroll
        for (int r = 0; r < 16; ++r) { sA[r] = fast_exp2(sA[r]); ls += sA[r]; }
        #pragma unroll
        for (int r = 0; r < 16; ++r) { sB[r] = fast_exp2(sB[r]); ls += sB[r]; }
        lrun += ls;

        unsigned dwv[2][4][2];
        #pragma unroll
        for (int j = 0; j < 4; ++j)
            #pragma unroll
            for (int c = 0; c < 2; ++c) {
                dwv[0][j][c] = pack2(sA[j * 4 + 2 * c], sA[j * 4 + 2 * c + 1]);
                dwv[1][j][c] = pack2(sB[j * 4 + 2 * c], sB[j * 4 + 2 * c + 1]);
            }
        unsigned rc[2][2][2];
        #pragma unroll
        for (int t2 = 0; t2 < 2; ++t2)
            #pragma unroll
            for (int k1 = 0; k1 < 2; ++k1)
                #pragma unroll
                for (int c = 0; c < 2; ++c) {
                    const unsigned snd = hi ? dwv[t2][2 * k1][c] : dwv[t2][2 * k1 + 1][c];
                    rc[t2][k1][c] = (unsigned)__shfl_xor((int)snd, 32, 64);
                }

        __builtin_amdgcn_s_setprio(1);
        #pragma unroll
        for (int ks = 0; ks < 4; ++ks) {
            const int t2 = ks >> 1, k1 = ks & 1;
            union { unsigned u[4]; bf8 v; } pfv;
            pfv.u[0] = hi ? rc[t2][k1][0] : dwv[t2][2 * k1][0];
            pfv.u[1] = hi ? rc[t2][k1][1] : dwv[t2][2 * k1][1];
            pfv.u[2] = hi ? dwv[t2][2 * k1 + 1][0] : rc[t2][k1][0];
            pfv.u[3] = hi ? dwv[t2][2 * k1 + 1][1] : rc[t2][k1][1];
            oacc0 = __builtin_amdgcn_mfma_f32_32x32x16_bf16(vf[ks * 2 + 0], pfv.v, oacc0, 0, 0, 0);
            oacc1 = __builtin_amdgcn_mfma_f32_32x32x16_bf16(vf[ks * 2 + 1], pfv.v, oacc1, 0, 0, 0);
        }
        __builtin_amdgcn_s_setprio(0);
    };

    const int tt0 = w * 16;
    loadK(kA, tt0);
    #pragma unroll 1
    for (int t = 0; t < 16; t += 2) {
        step(kA, kB, tt0 + t, true);
        step(kB, kA, tt0 + t + 1, t + 2 < 16);
    }

    // ---- per-warp partial -> LDS
    const float ltot = lrun + __shfl_xor(lrun, 32, 64);
    #pragma unroll
    for (int r = 0; r < 16; ++r) {
        const int d = (r & 3) + 8 * (r >> 2) + 4 * hi;
        o_sh[w][q5][d] = oacc0[r];
        o_sh[w][q5][32 + d] = oacc1[r];
    }
    if (hi == 0) l_sh[w][q5] = ltot;
    __syncthreads();

    // ---- cooperative merge -> bf16 aout row-major
    const int row = tid >> 3;
    const int d0 = (tid & 7) * 8;
    const float inv = 1.0f / (l_sh[0][row] + l_sh[1][row] + l_sh[2][row] + l_sh[3][row]);
    float vals[8];
    #pragma unroll
    for (int j = 0; j < 8; ++j)
        vals[j] = (o_sh[0][row][d0 + j] + o_sh[1][row][d0 + j]
                 + o_sh[2][row][d0 + j] + o_sh[3][row][d0 + j]) * inv;
    union { unsigned u[4]; bf8 v; } ov;
    ov.u[0] = pack2(vals[0], vals[1]); ov.u[1] = pack2(vals[2], vals[3]);
    ov.u[2] = pack2(vals[4], vals[5]); ov.u[3] = pack2(vals[6], vals[7]);
    *(bf8*)&aoutb[((size_t)b * SS + qtile * 32 + row) * HID + h * HD + d0] = ov.v;
}

// ---------------------------------------------------------------------------
// Output projection via MFMA: aout_bf16(8192x256) @ wo^T + bo -> out fp32.
// grid 512 = 256 stiles x 2 groups; each wave one 32x32 tile.
// ---------------------------------------------------------------------------
__global__ __launch_bounds__(256)
void out_proj_kernel(const __hip_bfloat16* __restrict__ aoutb,
                     const __hip_bfloat16* __restrict__ wpk,
                     const float* __restrict__ bo, float* __restrict__ out)
{
    const int bid = blockIdx.x;
    const int stile = bid >> 1, grp = bid & 1;
    const int tid = threadIdx.x;
    const int w = tid >> 6, lane = tid & 63, hi = lane >> 5, l5 = lane & 31;

    __shared__ __hip_bfloat16 xs[32][256];
    {
        const int r0 = tid >> 5, c = tid & 31;
        #pragma unroll
        for (int it = 0; it < 4; ++it) {
            const int row = r0 + it * 8;
            const bf8 v = *(const bf8*)&aoutb[(size_t)(stile * 32 + row) * HID + c * 8];
            *(bf8*)&xs[row][((c ^ row) & 31) * 8] = v;
        }
    }
    __syncthreads();

    const int nt = grp * 4 + w;           // 0..7
    const __hip_bfloat16* wb = wpk + (size_t)((3 * 8 + nt) * 16) * 512 + (size_t)lane * 8;
    bf8 wf[16];
    #pragma unroll
    for (int ks = 0; ks < 16; ++ks) wf[ks] = *(const bf8*)&wb[ks * 512];

    f16v acc;
    #pragma unroll
    for (int r = 0; r < 16; ++r) acc[r] = 0.0f;
    #pragma unroll
    for (int ks = 0; ks < 16; ++ks) {
        const bf8 xf = *(const bf8*)&xs[l5][(((ks * 2 + hi) ^ l5) & 31) * 8];
        acc = __builtin_amdgcn_mfma_f32_32x32x16_bf16(xf, wf[ks], acc, 0, 0, 0);
    }

    const float bn = bo[nt * 32 + l5];
    #pragma unroll
    for (int r = 0; r < 16; ++r) {
        const int sloc = (r & 3) + 8 * (r >> 2) + 4 * hi;
        out[(size_t)(stile * 32 + sloc) * HID + nt * 32 + l5] = acc[r] + bn;
    }
}

extern "C" void kernel_launch(void* const* d_in, const int* in_sizes, int n_in,
                              void* d_out, int out_size, void* d_ws, size_t ws_size,
                              hipStream_t stream)
{
    (void)in_sizes; (void)n_in; (void)out_size; (void)ws_size;
    const float* x        = (const float*)d_in[0];
    const int*   codons   = (const int*)d_in[1];
    const float* syn_bias = (const float*)d_in[2];
    const float* wq = (const float*)d_in[3];
    const float* bq = (const float*)d_in[4];
    const float* wk = (const float*)d_in[5];
    const float* bk = (const float*)d_in[6];
    const float* wv = (const float*)d_in[7];
    const float* bv = (const float*)d_in[8];
    const float* wo = (const float*)d_in[9];
    const float* bo = (const float*)d_in[10];
    float* out = (float*)d_out;

    char* ws = (char*)d_ws;
    int*   gid   = (int*)(ws);                                  // 256 B
    float* betaP = (float*)(ws + 256);                          // 4 B
    __hip_bfloat16* wpk   = (__hip_bfloat16*)(ws + 4096);       // 512 KB
    __hip_bfloat16* qfrag = (__hip_bfloat16*)(ws + (size_t)1048576u);    // 6 MB
    __hip_bfloat16* kfrag = (__hip_bfloat16*)(ws + (size_t)7340032u);    // 6 MB
    __hip_bfloat16* vfrag = (__hip_bfloat16*)(ws + (size_t)13631488u);   // 4 MB
    __hip_bfloat16* aoutb = (__hip_bfloat16*)(ws + (size_t)17825792u);   // 4 MB

    setup_kernel<<<1, 64, 0, stream>>>(syn_bias, gid, betaP);
    pack_w_kernel<<<128, 256, 0, stream>>>(wq, wk, wv, wo, wpk);
    qkv_mfma_kernel<<<1536, 256, 0, stream>>>(x, wpk, bq, bk, bv, codons, gid, betaP,
                                              qfrag, kfrag, vfrag);
    attn_kernel<<<1024, 256, 0, stream>>>(qfrag, kfrag, vfrag, aoutb);
    out_proj_kernel<<<512, 256, 0, stream>>>(aoutb, wpk, bo, out);
}